// Round 1
// baseline (3292.288 us; speedup 1.0000x reference)
//
#include <hip/hip_runtime.h>

#define NSITES 64
#define CHI 64
#define BATCH 32768

// ============================================================================
// Kernel 1: per-site Householder QR (LAPACK dgeqrf/dorgqr convention), f64.
// W: [64][64][2][64] f32 (site, l, s, r). For site i: Mt[sr][l] = W[i,l,s,r],
// Mt is 128x64. QR(Mt) = Q R with LAPACK sign convention. Output:
// A8[i*8192 + l*128 + sr] = Q[sr][l]   (i.e. A = Q^T reshaped [chi,2,chi])
// ============================================================================
__global__ __launch_bounds__(128) void qr_site_kernel(
    const float* __restrict__ W, double* __restrict__ A8)
{
    __shared__ double M[128][64];      // 64 KiB: working matrix / Householder v's
    __shared__ double wpart[2][64];
    __shared__ double tauS[64];
    __shared__ double redS[2];

    const int i   = blockIdx.x;
    const int tid = threadIdx.x;

    // load Mt: M[sr][l] = W[i*8192 + l*128 + sr]  (coalesced over idx)
    for (int idx = tid; idx < 8192; idx += 128) {
        int l = idx >> 7, sr = idx & 127;
        M[sr][l] = (double)W[i * 8192 + idx];
    }
    __syncthreads();

    const int jf = tid & 63;   // factor-phase column
    const int gf = tid >> 6;   // row group: rows [gf*64, gf*64+64)

    for (int k = 0; k < 64; ++k) {
        const double alpha = M[k][k];
        // ||x_rest||^2 over rows k+1..127 of column k
        double xv = (tid > k) ? M[tid][k] : 0.0;
        double v2 = xv * xv;
        #pragma unroll
        for (int off = 32; off > 0; off >>= 1) v2 += __shfl_down(v2, off, 64);
        if ((tid & 63) == 0) redS[tid >> 6] = v2;
        __syncthreads();
        const double xnorm2 = redS[0] + redS[1];

        double beta, tk;
        if (xnorm2 == 0.0) { beta = alpha; tk = 0.0; }
        else {
            double nrm = sqrt(alpha * alpha + xnorm2);
            beta = (alpha >= 0.0) ? -nrm : nrm;      // beta = -sign(alpha)*nrm
            tk   = (beta - alpha) / beta;
        }
        const double sc = (tk != 0.0) ? (1.0 / (alpha - beta)) : 0.0;
        __syncthreads();                         // all alpha/x reads done
        if (tid > k && tk != 0.0) M[tid][k] *= sc;   // v (v_k = 1 implicit)
        if (tid == 0) tauS[k] = tk;
        __syncthreads();

        // w_j = v^T M[:,j] (rows k..127), partials per row-group
        double part = 0.0;
        if (jf > k) {
            int m0 = (k > gf * 64) ? (k - gf * 64) : 0;
            for (int m = m0; m < 64; ++m) {
                int rr = gf * 64 + m;
                double vr = (rr == k) ? 1.0 : M[rr][k];
                part += vr * M[rr][jf];
            }
        }
        wpart[gf][jf] = part;
        __syncthreads();
        if (jf > k) {
            double wj = tk * (wpart[0][jf] + wpart[1][jf]);
            int m0 = (k > gf * 64) ? (k - gf * 64) : 0;
            for (int m = m0; m < 64; ++m) {
                int rr = gf * 64 + m;
                double vr = (rr == k) ? 1.0 : M[rr][k];
                M[rr][jf] -= vr * wj;
            }
        }
        __syncthreads();
    }

    // ---- form Q = H_0 ... H_63 applied to [I;0] (apply in reverse order) ----
    // thread owns column jq = tid>>1, row half gq = tid&1 (64 rows in regs)
    const int jq = tid >> 1;
    const int gq = tid & 1;
    double Ecol[64];
    #pragma unroll
    for (int m = 0; m < 64; ++m) Ecol[m] = ((gq * 64 + m) == jq) ? 1.0 : 0.0;

    for (int k = 63; k >= 0; --k) {
        const double tk = tauS[k];
        double part = 0.0;
        #pragma unroll
        for (int m = 0; m < 64; ++m) {
            int rr = gq * 64 + m;
            if (rr >= k) {
                double vr = (rr == k) ? 1.0 : M[rr][k];
                part += vr * Ecol[m];
            }
        }
        part += __shfl_xor(part, 1, 64);
        const double wj = tk * part;
        #pragma unroll
        for (int m = 0; m < 64; ++m) {
            int rr = gq * 64 + m;
            if (rr >= k) {
                double vr = (rr == k) ? 1.0 : M[rr][k];
                Ecol[m] -= vr * wj;
            }
        }
    }

    // store A8[i*8192 + jq*128 + (gq*64+m)] = Q[(gq*64+m)][jq]
    {
        double* dst = A8 + (size_t)i * 8192 + jq * 128 + gq * 64;
        #pragma unroll
        for (int m = 0; m < 64; ++m) dst[m] = Ecol[m];
    }
}

// ============================================================================
// Kernel 2: sequential perfect sampling. 2 lanes per batch element (split the
// l=64 contraction dim in half). 256 blocks x 256 threads = 2*BATCH lanes.
// f64 throughout. A_i staged in LDS (64 KiB) + chosen-T buffer (64 KiB).
// ============================================================================
__global__ __launch_bounds__(256) void sample_kernel(
    const double* __restrict__ A8, const float* __restrict__ u,
    float* __restrict__ out)
{
    __shared__ __align__(16) double As[8192];   // A_i: [l*128 + sr]
    __shared__ double St[32][256];              // chosen T, own half, per thread

    const int tid = threadIdx.x;
    const int b   = blockIdx.x * 128 + (tid >> 1);
    const int h   = tid & 1;                    // which half of l this lane owns

    double Lh[32];
    #pragma unroll
    for (int j = 0; j < 32; ++j) Lh[j] = 0.0;
    if (h == 0) Lh[0] = 1.0;                    // L0 = e_0

    float* probOut = out + (size_t)BATCH * (NSITES * 2);

    for (int site = 0; site < NSITES; ++site) {
        __syncthreads();                        // prev readers of As done
        {   // stage A_i (coalesced)
            const double* src = A8 + (size_t)site * 8192;
            #pragma unroll
            for (int t = 0; t < 32; ++t) As[t * 256 + tid] = src[t * 256 + tid];
        }
        __syncthreads();

        const float uv = u[(size_t)b * NSITES + site];
        const double* Abase = As + h * (32 * 128);

        // ---------- pass 1: s = 0, compute p0 and stash own-half T0 ----------
        double p0 = 0.0;
        #pragma unroll 2
        for (int rq = 0; rq < 16; ++rq) {
            const int sr = rq * 4;
            double a0 = 0.0, a1 = 0.0, a2 = 0.0, a3 = 0.0;
            const double* Ap = Abase + sr;
            #pragma unroll
            for (int j = 0; j < 32; ++j) {
                const double* q = Ap + j * 128;
                double2 v01 = *(const double2*)(q);
                double2 v23 = *(const double2*)(q + 2);
                a0 = fma(Lh[j], v01.x, a0);
                a1 = fma(Lh[j], v01.y, a1);
                a2 = fma(Lh[j], v23.x, a2);
                a3 = fma(Lh[j], v23.y, a3);
            }
            a0 += __shfl_xor(a0, 1, 64);
            a1 += __shfl_xor(a1, 1, 64);
            a2 += __shfl_xor(a2, 1, 64);
            a3 += __shfl_xor(a3, 1, 64);
            p0 = fma(a0, a0, p0); p0 = fma(a1, a1, p0);
            p0 = fma(a2, a2, p0); p0 = fma(a3, a3, p0);
            if ((rq >> 3) == h) {               // own half of r
                const int jo = sr & 31;
                St[jo + 0][tid] = a0; St[jo + 1][tid] = a1;
                St[jo + 2][tid] = a2; St[jo + 3][tid] = a3;
            }
        }

        const bool take1  = ((double)uv >= p0);
        const double psel = take1 ? (1.0 - p0) : p0;   // p0+p1==1 by isometry
        const double invs = 1.0 / sqrt(psel);

        // ---------- pass 2: s = 1, overwrite stash where take1 ----------
        #pragma unroll 2
        for (int rq = 0; rq < 16; ++rq) {
            const int sr = 64 + rq * 4;
            double a0 = 0.0, a1 = 0.0, a2 = 0.0, a3 = 0.0;
            const double* Ap = Abase + sr;
            #pragma unroll
            for (int j = 0; j < 32; ++j) {
                const double* q = Ap + j * 128;
                double2 v01 = *(const double2*)(q);
                double2 v23 = *(const double2*)(q + 2);
                a0 = fma(Lh[j], v01.x, a0);
                a1 = fma(Lh[j], v01.y, a1);
                a2 = fma(Lh[j], v23.x, a2);
                a3 = fma(Lh[j], v23.y, a3);
            }
            a0 += __shfl_xor(a0, 1, 64);
            a1 += __shfl_xor(a1, 1, 64);
            a2 += __shfl_xor(a2, 1, 64);
            a3 += __shfl_xor(a3, 1, 64);
            if (take1 && (((sr - 64) >> 5) == h)) {
                const int jo = (sr - 64) & 31;
                St[jo + 0][tid] = a0; St[jo + 1][tid] = a1;
                St[jo + 2][tid] = a2; St[jo + 3][tid] = a3;
            }
        }

        // L update: renormalize chosen T (own half; r becomes next site's l)
        #pragma unroll
        for (int j = 0; j < 32; ++j) Lh[j] = St[j][tid] * invs;

        if (h == 0) {
            probOut[(size_t)b * NSITES + site] = (float)psel;
            // s_hat = one_hot(1-s): s=0 -> [0,1], s=1 -> [1,0]
            float2 sh;
            sh.x = take1 ? 1.0f : 0.0f;
            sh.y = take1 ? 0.0f : 1.0f;
            *(float2*)(out + (size_t)b * (NSITES * 2) + site * 2) = sh;
        }
    }
}

extern "C" void kernel_launch(void* const* d_in, const int* in_sizes, int n_in,
                              void* d_out, int out_size, void* d_ws, size_t ws_size,
                              hipStream_t stream)
{
    const float* W = (const float*)d_in[0];   // [64,64,2,64] f32
    const float* u = (const float*)d_in[1];   // [32768,64] f32
    float* out = (float*)d_out;               // s_hat [B,64,2] then prob [B,64]
    double* A8 = (double*)d_ws;               // isometrized A, f64, 4 MiB

    hipLaunchKernelGGL(qr_site_kernel, dim3(NSITES), dim3(128), 0, stream, W, A8);
    hipLaunchKernelGGL(sample_kernel, dim3(256), dim3(256), 0, stream, A8, u, out);
}

// Round 2
// 1750.276 us; speedup vs baseline: 1.8810x; 1.8810x over previous
//
#include <hip/hip_runtime.h>

#define NSITES 64
#define CHI 64
#define BATCH 32768

// ============================================================================
// Kernel 1: per-site Householder QR (LAPACK dgeqrf/dorgqr convention), f64.
// W: [64][64][2][64] f32 (site, l, s, r). For site i: Mt[sr][l] = W[i,l,s,r],
// Mt is 128x64. QR(Mt) = Q R, LAPACK sign convention (beta = -sign(a)*nrm).
// Output: A8[i*8192 + l*128 + sr] = Q[sr][l].
// 256 threads: factor phase = 64 cols x 4 row-quarters; Q phase = col jq=tid>>2,
// row-quarter qq=tid&3 with E[32] in regs (no spill) + 2-level shfl combine.
// ============================================================================
__global__ __launch_bounds__(256) void qr_site_kernel(
    const float* __restrict__ W, double* __restrict__ A8)
{
    __shared__ double M[128][65];     // padded: stride 65*8=520B breaks bank alias
    __shared__ double wpart[4][64];
    __shared__ double tauS[64];
    __shared__ double redS[2];

    const int i   = blockIdx.x;
    const int tid = threadIdx.x;

    for (int idx = tid; idx < 8192; idx += 256) {
        int l = idx >> 7, sr = idx & 127;
        M[sr][l] = (double)W[i * 8192 + idx];
    }
    __syncthreads();

    const int jf = tid & 63;          // column
    const int gf = tid >> 6;          // row quarter: rows [gf*32, gf*32+32)

    for (int k = 0; k < 64; ++k) {
        const double alpha = M[k][k];
        double v2 = 0.0;
        if (tid < 128) { double xv = (tid > k) ? M[tid][k] : 0.0; v2 = xv * xv; }
        #pragma unroll
        for (int off = 32; off; off >>= 1) v2 += __shfl_down(v2, off, 64);
        if (tid < 128 && (tid & 63) == 0) redS[tid >> 6] = v2;
        __syncthreads();
        const double xnorm2 = redS[0] + redS[1];

        double beta, tk;
        if (xnorm2 == 0.0) { beta = alpha; tk = 0.0; }
        else {
            double nrm = sqrt(alpha * alpha + xnorm2);
            beta = (alpha >= 0.0) ? -nrm : nrm;
            tk   = (beta - alpha) / beta;
        }
        const double sc = (tk != 0.0) ? (1.0 / (alpha - beta)) : 0.0;
        if (tid < 128 && tid > k && tk != 0.0) M[tid][k] *= sc;  // v (v_k=1 implicit)
        if (tid == 0) tauS[k] = tk;
        __syncthreads();

        // w_j = v^T M[:,j] over rows k..127, split in 4 row-quarters
        double part = 0.0;
        const int r0 = gf * 32;
        const int m0 = (k + 1 > r0) ? (k + 1 - r0) : 0;
        if (jf > k) {
            if (k >= r0 && k < r0 + 32) part += M[k][jf];        // v_k = 1
            for (int m = m0; m < 32; ++m) {
                int rr = r0 + m;
                part = fma(M[rr][k], M[rr][jf], part);
            }
        }
        wpart[gf][jf] = part;
        __syncthreads();
        if (jf > k) {
            double wj = tauS[k] * (wpart[0][jf] + wpart[1][jf] + wpart[2][jf] + wpart[3][jf]);
            if (k >= r0 && k < r0 + 32) M[k][jf] -= wj;
            for (int m = m0; m < 32; ++m) {
                int rr = r0 + m;
                M[rr][jf] = fma(-M[rr][k], wj, M[rr][jf]);
            }
        }
        __syncthreads();
    }

    // ---- Q = H_0 ... H_63 applied to [I;0], reverse order ----
    const int jq = tid >> 2;          // column 0..63
    const int qq = tid & 3;           // row quarter
    double E[32];
    #pragma unroll
    for (int m = 0; m < 32; ++m) E[m] = ((qq * 32 + m) == jq) ? 1.0 : 0.0;

    for (int k = 63; k >= 0; --k) {
        const double tk = tauS[k];
        double part = 0.0;
        #pragma unroll
        for (int m = 0; m < 32; ++m) {
            int rr = qq * 32 + m;
            if (rr > k)       part = fma(M[rr][k], E[m], part);
            else if (rr == k) part += E[m];
        }
        part += __shfl_xor(part, 1, 64);
        part += __shfl_xor(part, 2, 64);
        const double wj = tk * part;
        #pragma unroll
        for (int m = 0; m < 32; ++m) {
            int rr = qq * 32 + m;
            if (rr > k)       E[m] = fma(-M[rr][k], wj, E[m]);
            else if (rr == k) E[m] -= wj;
        }
    }

    double* dst = A8 + (size_t)i * 8192 + jq * 128 + qq * 32;
    #pragma unroll
    for (int m = 0; m < 32; ++m) dst[m] = E[m];
}

// ============================================================================
// Kernel 2: sequential perfect sampling, r-split.
// 8 lanes per batch element; lane rlane owns sr in {2*rlane+16t, +1 : t=0..7}
// (conflict-free b128 LDS reads: banks 4*rlane..4*rlane+3, 8-way broadcast).
// L lives in LDS transposed [l][128 batches] -> reads/writes conflict-free-ish,
// and each batch's L column is touched only by its own wave (no barrier).
// 256 blocks x 1024 threads = 16 waves/CU = 4 waves/SIMD.
// ============================================================================
__global__ __launch_bounds__(1024, 4) void sample_kernel(
    const double* __restrict__ A8, const float* __restrict__ u,
    float* __restrict__ out)
{
    __shared__ __align__(16) double As[8192];    // A_i: [l*128 + sr], 64 KiB
    __shared__ double Lds[8192];                 // L: [l*128 + bloc], 64 KiB

    const int tid   = threadIdx.x;
    const int bloc  = tid >> 3;                  // batch-in-block 0..127
    const int rlane = tid & 7;                   // r-slice owner 0..7
    const int b     = blockIdx.x * 128 + bloc;
    const int rbase = 2 * rlane;

    // init L = e_0 (each lane initializes exactly its own 8 slots)
    {
        double* Lw = Lds + bloc;
        Lw[(rbase + 0) * 128]  = (rbase == 0) ? 1.0 : 0.0;
        Lw[(rbase + 1) * 128]  = 0.0;
        Lw[(rbase + 16) * 128] = 0.0;
        Lw[(rbase + 17) * 128] = 0.0;
        Lw[(rbase + 32) * 128] = 0.0;
        Lw[(rbase + 33) * 128] = 0.0;
        Lw[(rbase + 48) * 128] = 0.0;
        Lw[(rbase + 49) * 128] = 0.0;
    }

    float* probOut = out + (size_t)BATCH * (NSITES * 2);

    for (int site = 0; site < NSITES; ++site) {
        __syncthreads();                         // all waves done reading As
        {   // stage A_i (coalesced double2)
            const double2* s2 = (const double2*)(A8 + (size_t)site * 8192);
            double2* a2 = (double2*)As;
            #pragma unroll
            for (int q = 0; q < 4; ++q) a2[q * 1024 + tid] = s2[q * 1024 + tid];
        }
        __syncthreads();

        double acc0 = 0, acc1 = 0, acc2 = 0, acc3 = 0, acc4 = 0, acc5 = 0, acc6 = 0, acc7 = 0;
        double acc8 = 0, acc9 = 0, acc10 = 0, acc11 = 0, acc12 = 0, acc13 = 0, acc14 = 0, acc15 = 0;

        const double* Lp = Lds + bloc;
        const double* Ab = As + rbase;
        #pragma unroll 8
        for (int j = 0; j < 64; ++j) {
            const double Lj = Lp[j * 128];
            const double* Ap = Ab + j * 128;
            double2 v;
            v = *(const double2*)(Ap +   0); acc0  = fma(Lj, v.x, acc0 ); acc1  = fma(Lj, v.y, acc1 );
            v = *(const double2*)(Ap +  16); acc2  = fma(Lj, v.x, acc2 ); acc3  = fma(Lj, v.y, acc3 );
            v = *(const double2*)(Ap +  32); acc4  = fma(Lj, v.x, acc4 ); acc5  = fma(Lj, v.y, acc5 );
            v = *(const double2*)(Ap +  48); acc6  = fma(Lj, v.x, acc6 ); acc7  = fma(Lj, v.y, acc7 );
            v = *(const double2*)(Ap +  64); acc8  = fma(Lj, v.x, acc8 ); acc9  = fma(Lj, v.y, acc9 );
            v = *(const double2*)(Ap +  80); acc10 = fma(Lj, v.x, acc10); acc11 = fma(Lj, v.y, acc11);
            v = *(const double2*)(Ap +  96); acc12 = fma(Lj, v.x, acc12); acc13 = fma(Lj, v.y, acc13);
            v = *(const double2*)(Ap + 112); acc14 = fma(Lj, v.x, acc14); acc15 = fma(Lj, v.y, acc15);
        }

        // p0 = |T0|^2 : own partial then butterfly over the 8 lanes of the batch.
        // xor-butterfly is commutative-symmetric -> bit-identical on all 8 lanes.
        double p0 = acc0 * acc0;
        p0 = fma(acc1, acc1, p0); p0 = fma(acc2, acc2, p0); p0 = fma(acc3, acc3, p0);
        p0 = fma(acc4, acc4, p0); p0 = fma(acc5, acc5, p0); p0 = fma(acc6, acc6, p0);
        p0 = fma(acc7, acc7, p0);
        p0 += __shfl_xor(p0, 1, 64);
        p0 += __shfl_xor(p0, 2, 64);
        p0 += __shfl_xor(p0, 4, 64);

        const float uv = u[(size_t)b * NSITES + site];
        const bool take1   = ((double)uv >= p0);
        const double psel  = take1 ? (1.0 - p0) : p0;     // p0+p1==1 by isometry
        const double invs  = 1.0 / sqrt(psel);

        // chosen T -> new L (own 8 r-slots; same-wave only, no barrier needed)
        {
            double* Lw = Lds + bloc;
            Lw[(rbase + 0) * 128]  = (take1 ? acc8  : acc0) * invs;
            Lw[(rbase + 1) * 128]  = (take1 ? acc9  : acc1) * invs;
            Lw[(rbase + 16) * 128] = (take1 ? acc10 : acc2) * invs;
            Lw[(rbase + 17) * 128] = (take1 ? acc11 : acc3) * invs;
            Lw[(rbase + 32) * 128] = (take1 ? acc12 : acc4) * invs;
            Lw[(rbase + 33) * 128] = (take1 ? acc13 : acc5) * invs;
            Lw[(rbase + 48) * 128] = (take1 ? acc14 : acc6) * invs;
            Lw[(rbase + 49) * 128] = (take1 ? acc15 : acc7) * invs;
        }

        if (rlane == 0) {
            probOut[(size_t)b * NSITES + site] = (float)psel;
            float2 sh;
            sh.x = take1 ? 1.0f : 0.0f;
            sh.y = take1 ? 0.0f : 1.0f;
            *(float2*)(out + (size_t)b * (NSITES * 2) + site * 2) = sh;
        }
    }
}

extern "C" void kernel_launch(void* const* d_in, const int* in_sizes, int n_in,
                              void* d_out, int out_size, void* d_ws, size_t ws_size,
                              hipStream_t stream)
{
    const float* W = (const float*)d_in[0];   // [64,64,2,64] f32
    const float* u = (const float*)d_in[1];   // [32768,64] f32
    float* out = (float*)d_out;               // s_hat [B,64,2] then prob [B,64]
    double* A8 = (double*)d_ws;               // isometrized A, f64, 4 MiB

    hipLaunchKernelGGL(qr_site_kernel, dim3(NSITES), dim3(256), 0, stream, W, A8);
    hipLaunchKernelGGL(sample_kernel, dim3(256), dim3(1024), 0, stream, A8, u, out);
}

// Round 3
// 1724.120 us; speedup vs baseline: 1.9095x; 1.0152x over previous
//
#include <hip/hip_runtime.h>

#define NSITES 64
#define CHI 64
#define BATCH 32768
#define LSTRIDE 132   // doubles per L row: 132*8=1056B -> bank base 8*r+4*c (spreads rows)

// ============================================================================
// Kernel 1: per-site Householder QR (LAPACK dgeqrf/dorgqr convention), f64.
// Mt[sr][l] = W[i,l,s,r] (128x64); QR with beta = -sign(alpha)*nrm.
// Output: A8[i*8192 + l*128 + sr] = Q[sr][l].
// 512 threads. Factor: 64 cols x 8 row-groups of 16. Q-phase: col jq=tid>>3,
// row-octant qq=tid&7, E[16] in regs; v staged per-k in padded vcol[] to kill
// the 8-way bank conflict (rows 16 apart alias mod 32 banks in M).
// ============================================================================
__global__ __launch_bounds__(512) void qr_site_kernel(
    const float* __restrict__ W, double* __restrict__ A8)
{
    __shared__ double M[128][65];
    __shared__ double wpart[8][64];
    __shared__ double tauS[64];
    __shared__ double redS[2];
    __shared__ double vcol[136];          // idx = r + (r>>4): conflict-free octants

    const int i   = blockIdx.x;
    const int tid = threadIdx.x;

    for (int idx = tid; idx < 8192; idx += 512) {
        int l = idx >> 7, sr = idx & 127;
        M[sr][l] = (double)W[i * 8192 + idx];
    }
    __syncthreads();

    const int jf = tid & 63;              // column
    const int gf = tid >> 6;              // row group 0..7 (rows gf*16..+16)
    const int r0 = gf * 16;

    for (int k = 0; k < 64; ++k) {
        const double alpha = M[k][k];
        double v2 = 0.0;
        if (tid < 128) { double xv = (tid > k) ? M[tid][k] : 0.0; v2 = xv * xv; }
        #pragma unroll
        for (int off = 32; off; off >>= 1) v2 += __shfl_down(v2, off, 64);
        if (tid < 128 && (tid & 63) == 0) redS[tid >> 6] = v2;
        __syncthreads();
        const double xnorm2 = redS[0] + redS[1];

        double beta, tk;
        if (xnorm2 == 0.0) { beta = alpha; tk = 0.0; }
        else {
            double nrm = sqrt(alpha * alpha + xnorm2);
            beta = (alpha >= 0.0) ? -nrm : nrm;
            tk   = (beta - alpha) / beta;
        }
        const double sc = (tk != 0.0) ? (1.0 / (alpha - beta)) : 0.0;
        if (tid < 128 && tid > k && tk != 0.0) M[tid][k] *= sc;  // v (v_k=1 implicit)
        if (tid == 0) tauS[k] = tk;
        __syncthreads();

        double part = 0.0;
        if (jf > k) {
            #pragma unroll 4
            for (int m = 0; m < 16; ++m) {
                int rr = r0 + m;   // M[rr][k] is wave-uniform (gf fixed/wave) -> broadcast
                double vr = (rr > k) ? M[rr][k] : ((rr == k) ? 1.0 : 0.0);
                part = fma(vr, M[rr][jf], part);
            }
        }
        wpart[gf][jf] = part;
        __syncthreads();
        if (jf > k) {
            double wj = tauS[k] * (wpart[0][jf] + wpart[1][jf] + wpart[2][jf] + wpart[3][jf]
                                 + wpart[4][jf] + wpart[5][jf] + wpart[6][jf] + wpart[7][jf]);
            #pragma unroll 4
            for (int m = 0; m < 16; ++m) {
                int rr = r0 + m;
                double vr = (rr > k) ? M[rr][k] : ((rr == k) ? 1.0 : 0.0);
                M[rr][jf] = fma(-vr, wj, M[rr][jf]);
            }
        }
        __syncthreads();
    }

    // ---- Q = H_0 ... H_63 applied to [I;0], reverse order ----
    const int jq = tid >> 3;              // column 0..63
    const int qq = tid & 7;               // row octant
    double E[16];
    #pragma unroll
    for (int m = 0; m < 16; ++m) E[m] = ((qq * 16 + m) == jq) ? 1.0 : 0.0;

    for (int k = 63; k >= 0; --k) {
        if (tid < 128) {
            double val = (tid > k) ? M[tid][k] : ((tid == k) ? 1.0 : 0.0);
            vcol[tid + (tid >> 4)] = val;
        }
        __syncthreads();
        const double tk = tauS[k];
        double part = 0.0;
        #pragma unroll
        for (int m = 0; m < 16; ++m) {
            int rr = qq * 16 + m;
            part = fma(vcol[rr + qq], E[m], part);   // zeros contribute exactly 0
        }
        part += __shfl_xor(part, 1, 64);
        part += __shfl_xor(part, 2, 64);
        part += __shfl_xor(part, 4, 64);
        const double wj = tk * part;
        #pragma unroll
        for (int m = 0; m < 16; ++m) {
            int rr = qq * 16 + m;
            E[m] = fma(-vcol[rr + qq], wj, E[m]);
        }
        __syncthreads();                  // before next k overwrites vcol
    }

    double* dst = A8 + (size_t)i * 8192 + jq * 128 + qq * 16;
    #pragma unroll
    for (int m = 0; m < 16; ++m) dst[m] = E[m];
}

// ============================================================================
// Kernel 2: sequential perfect sampling, r-split + 2-batch register blocking.
// 512 thr/block: lane = (c = tid>>3 batch-pair 0..63, rlane = tid&7).
// Lane handles batches b0 = blk*128+c and b1 = b0+64; owns sr slices
// {2*rlane+16t, +1} (conflict-free b128 A reads, 8-way broadcast, SHARED by
// both batches -> halves LDS request rate vs 1 batch/lane).
// L: [l][2c+g] pair layout, stride 132 -> one b128 read per j for both
// batches (conflict-free), 4-way-only writes. Chosen T stays in registers.
// Async-stage split: prefetch next site's A into regs during compute.
// ============================================================================
__global__ __launch_bounds__(512, 2) void sample_kernel(
    const double* __restrict__ A8, const float* __restrict__ u,
    float* __restrict__ out)
{
    __shared__ __align__(16) double As[8192];            // A_i: [l*128+sr], 64 KiB
    __shared__ __align__(16) double Lds[64 * LSTRIDE];   // 66 KiB

    const int tid   = threadIdx.x;
    const int c     = tid >> 3;          // batch pair 0..63
    const int rlane = tid & 7;
    const int rbase = 2 * rlane;
    const int b0    = blockIdx.x * 128 + c;
    const int b1    = b0 + 64;

    // init L = e_0 for both batches (own 8 rows; same-wave only)
    #pragma unroll
    for (int t = 0; t < 8; ++t) {
        int r = rbase + ((t >> 1) << 4) + (t & 1);
        double v = (r == 0) ? 1.0 : 0.0;
        *(double2*)(Lds + r * LSTRIDE + 2 * c) = make_double2(v, v);
    }

    {   // stage site 0
        const double2* s2 = (const double2*)A8;
        double2* a2 = (double2*)As;
        #pragma unroll
        for (int q = 0; q < 8; ++q) a2[q * 512 + tid] = s2[q * 512 + tid];
    }
    __syncthreads();

    float* probOut = out + (size_t)BATCH * (NSITES * 2);

    for (int site = 0; site < NSITES; ++site) {
        // prefetch next site's A into registers (hides under compute)
        double2 pre[8];
        {
            const int nsrc = (site < NSITES - 1) ? site + 1 : site;
            const double2* s2 = (const double2*)(A8 + (size_t)nsrc * 8192);
            #pragma unroll
            for (int q = 0; q < 8; ++q) pre[q] = s2[q * 512 + tid];
        }

        double acc0[16], acc1[16];
        #pragma unroll
        for (int t = 0; t < 16; ++t) { acc0[t] = 0.0; acc1[t] = 0.0; }

        const double* Ab = As + rbase;
        #pragma unroll 8
        for (int j = 0; j < 64; ++j) {
            const double2 Lv = *(const double2*)(Lds + j * LSTRIDE + 2 * c);
            const double* Ap = Ab + j * 128;
            #pragma unroll
            for (int t = 0; t < 8; ++t) {
                double2 v = *(const double2*)(Ap + t * 16);
                acc0[2*t]   = fma(Lv.x, v.x, acc0[2*t]);
                acc0[2*t+1] = fma(Lv.x, v.y, acc0[2*t+1]);
                acc1[2*t]   = fma(Lv.y, v.x, acc1[2*t]);
                acc1[2*t+1] = fma(Lv.y, v.y, acc1[2*t+1]);
            }
        }

        // p0 per batch (acc[0..7] = s=0 slice, same fma order as prev round),
        // then xor-butterfly over the batch's 8 lanes (symmetric, identical on all).
        double pa = acc0[0] * acc0[0];
        #pragma unroll
        for (int t = 1; t < 8; ++t) pa = fma(acc0[t], acc0[t], pa);
        double pb = acc1[0] * acc1[0];
        #pragma unroll
        for (int t = 1; t < 8; ++t) pb = fma(acc1[t], acc1[t], pb);
        pa += __shfl_xor(pa, 1, 64); pa += __shfl_xor(pa, 2, 64); pa += __shfl_xor(pa, 4, 64);
        pb += __shfl_xor(pb, 1, 64); pb += __shfl_xor(pb, 2, 64); pb += __shfl_xor(pb, 4, 64);

        const float u0 = u[(size_t)b0 * NSITES + site];
        const float u1 = u[(size_t)b1 * NSITES + site];
        const bool  t1a = ((double)u0 >= pa);
        const bool  t1b = ((double)u1 >= pb);
        const double psa = t1a ? (1.0 - pa) : pa;     // p0+p1==1 by isometry
        const double psb = t1b ? (1.0 - pb) : pb;
        const double ia  = 1.0 / sqrt(psa);
        const double ib  = 1.0 / sqrt(psb);

        // chosen T -> new L (registers -> own 8 rows; same-wave, no barrier)
        #pragma unroll
        for (int t = 0; t < 8; ++t) {
            int r = rbase + ((t >> 1) << 4) + (t & 1);
            double va = (t1a ? acc0[8 + t] : acc0[t]) * ia;
            double vb = (t1b ? acc1[8 + t] : acc1[t]) * ib;
            *(double2*)(Lds + r * LSTRIDE + 2 * c) = make_double2(va, vb);
        }

        if (rlane == 0) {
            probOut[(size_t)b0 * NSITES + site] = (float)psa;
            probOut[(size_t)b1 * NSITES + site] = (float)psb;
            *(float2*)(out + (size_t)b0 * (NSITES * 2) + site * 2)
                = make_float2(t1a ? 1.f : 0.f, t1a ? 0.f : 1.f);
            *(float2*)(out + (size_t)b1 * (NSITES * 2) + site * 2)
                = make_float2(t1b ? 1.f : 0.f, t1b ? 0.f : 1.f);
        }

        __syncthreads();                  // all waves done reading As
        if (site < NSITES - 1) {
            double2* a2 = (double2*)As;
            #pragma unroll
            for (int q = 0; q < 8; ++q) a2[q * 512 + tid] = pre[q];
        }
        __syncthreads();
    }
}

extern "C" void kernel_launch(void* const* d_in, const int* in_sizes, int n_in,
                              void* d_out, int out_size, void* d_ws, size_t ws_size,
                              hipStream_t stream)
{
    const float* W = (const float*)d_in[0];   // [64,64,2,64] f32
    const float* u = (const float*)d_in[1];   // [32768,64] f32
    float* out = (float*)d_out;               // s_hat [B,64,2] then prob [B,64]
    double* A8 = (double*)d_ws;               // isometrized A, f64, 4 MiB

    hipLaunchKernelGGL(qr_site_kernel, dim3(NSITES), dim3(512), 0, stream, W, A8);
    hipLaunchKernelGGL(sample_kernel, dim3(256), dim3(512), 0, stream, A8, u, out);
}

// Round 4
// 1186.451 us; speedup vs baseline: 2.7749x; 1.4532x over previous
//
#include <hip/hip_runtime.h>

#define NSITES 64
#define CHI 64
#define BATCH 32768
#define LSTRIDE 132   // L row: 128 batch-doubles + 4 pad; 1056B stride, 16B aligned

// ============================================================================
// Kernel 1: per-site Householder QR (LAPACK dgeqrf/dorgqr convention), f64.
// Mt[sr][l] = W[i,l,s,r] (128x64); QR with beta = -sign(alpha)*nrm.
// Output: A8[i*8192 + l*128 + sr] = Q[sr][l].   [unchanged from round 3 - passing]
// ============================================================================
__global__ __launch_bounds__(512) void qr_site_kernel(
    const float* __restrict__ W, double* __restrict__ A8)
{
    __shared__ double M[128][65];
    __shared__ double wpart[8][64];
    __shared__ double tauS[64];
    __shared__ double redS[2];
    __shared__ double vcol[136];          // idx = r + (r>>4): conflict-free octants

    const int i   = blockIdx.x;
    const int tid = threadIdx.x;

    for (int idx = tid; idx < 8192; idx += 512) {
        int l = idx >> 7, sr = idx & 127;
        M[sr][l] = (double)W[i * 8192 + idx];
    }
    __syncthreads();

    const int jf = tid & 63;              // column
    const int gf = tid >> 6;              // row group 0..7 (rows gf*16..+16)
    const int r0 = gf * 16;

    for (int k = 0; k < 64; ++k) {
        const double alpha = M[k][k];
        double v2 = 0.0;
        if (tid < 128) { double xv = (tid > k) ? M[tid][k] : 0.0; v2 = xv * xv; }
        #pragma unroll
        for (int off = 32; off; off >>= 1) v2 += __shfl_down(v2, off, 64);
        if (tid < 128 && (tid & 63) == 0) redS[tid >> 6] = v2;
        __syncthreads();
        const double xnorm2 = redS[0] + redS[1];

        double beta, tk;
        if (xnorm2 == 0.0) { beta = alpha; tk = 0.0; }
        else {
            double nrm = sqrt(alpha * alpha + xnorm2);
            beta = (alpha >= 0.0) ? -nrm : nrm;
            tk   = (beta - alpha) / beta;
        }
        const double sc = (tk != 0.0) ? (1.0 / (alpha - beta)) : 0.0;
        if (tid < 128 && tid > k && tk != 0.0) M[tid][k] *= sc;  // v (v_k=1 implicit)
        if (tid == 0) tauS[k] = tk;
        __syncthreads();

        double part = 0.0;
        if (jf > k) {
            #pragma unroll 4
            for (int m = 0; m < 16; ++m) {
                int rr = r0 + m;
                double vr = (rr > k) ? M[rr][k] : ((rr == k) ? 1.0 : 0.0);
                part = fma(vr, M[rr][jf], part);
            }
        }
        wpart[gf][jf] = part;
        __syncthreads();
        if (jf > k) {
            double wj = tauS[k] * (wpart[0][jf] + wpart[1][jf] + wpart[2][jf] + wpart[3][jf]
                                 + wpart[4][jf] + wpart[5][jf] + wpart[6][jf] + wpart[7][jf]);
            #pragma unroll 4
            for (int m = 0; m < 16; ++m) {
                int rr = r0 + m;
                double vr = (rr > k) ? M[rr][k] : ((rr == k) ? 1.0 : 0.0);
                M[rr][jf] = fma(-vr, wj, M[rr][jf]);
            }
        }
        __syncthreads();
    }

    // ---- Q = H_0 ... H_63 applied to [I;0], reverse order ----
    const int jq = tid >> 3;              // column 0..63
    const int qq = tid & 7;               // row octant
    double E[16];
    #pragma unroll
    for (int m = 0; m < 16; ++m) E[m] = ((qq * 16 + m) == jq) ? 1.0 : 0.0;

    for (int k = 63; k >= 0; --k) {
        if (tid < 128) {
            double val = (tid > k) ? M[tid][k] : ((tid == k) ? 1.0 : 0.0);
            vcol[tid + (tid >> 4)] = val;
        }
        __syncthreads();
        const double tk = tauS[k];
        double part = 0.0;
        #pragma unroll
        for (int m = 0; m < 16; ++m) {
            int rr = qq * 16 + m;
            part = fma(vcol[rr + qq], E[m], part);
        }
        part += __shfl_xor(part, 1, 64);
        part += __shfl_xor(part, 2, 64);
        part += __shfl_xor(part, 4, 64);
        const double wj = tk * part;
        #pragma unroll
        for (int m = 0; m < 16; ++m) {
            int rr = qq * 16 + m;
            E[m] = fma(-vcol[rr + qq], wj, E[m]);
        }
        __syncthreads();
    }

    double* dst = A8 + (size_t)i * 8192 + jq * 128 + qq * 16;
    #pragma unroll
    for (int m = 0; m < 16; ++m) dst[m] = E[m];
}

// ============================================================================
// Kernel 2: sequential perfect sampling, 16-way r-split, G=4 batch blocking.
// 512 thr/block: group c = tid>>4 (32 groups), rlane = tid&15.
// Lane owns sr in {2*rlane + 32t + d : t=0..3, d=0..1} (slots s = 2t+d),
// serves 4 batches bb + 32*g (bb = blk*128 + c). Per j: 4 b128 A-reads shared
// by 4 batches + 2 b128 L-reads -> LDS ~240 cyc/j/CU < VALU 256 cyc/j/CU.
// ALL per-thread state in NAMED SCALARS (round-3 arrays spilled: 1 GB scratch).
// L layout [r][4c+g], stride LSTRIDE; reads/writes <=2-way conflicts.
// ============================================================================
#define FMA4(OFF, S0, S1) do {                                              \
    const double2 v = *(const double2*)(Ap + (OFF));                        \
    A0##S0 = fma(Lv01.x, v.x, A0##S0); A0##S1 = fma(Lv01.x, v.y, A0##S1);   \
    A1##S0 = fma(Lv01.y, v.x, A1##S0); A1##S1 = fma(Lv01.y, v.y, A1##S1);   \
    A2##S0 = fma(Lv23.x, v.x, A2##S0); A2##S1 = fma(Lv23.x, v.y, A2##S1);   \
    A3##S0 = fma(Lv23.y, v.x, A3##S0); A3##S1 = fma(Lv23.y, v.y, A3##S1);   \
} while (0)

__global__ __launch_bounds__(512, 2) void sample_kernel(
    const double* __restrict__ A8, const float* __restrict__ u,
    float* __restrict__ out)
{
    __shared__ __align__(16) double As[8192];            // A_i: [l*128+sr], 64 KiB
    __shared__ __align__(16) double Lds[64 * LSTRIDE];   // 66 KiB

    const int tid   = threadIdx.x;
    const int c     = tid >> 4;          // group 0..31
    const int rlane = tid & 15;
    const int rbase = 2 * rlane;
    const int bb    = blockIdx.x * 128 + c;   // batches: bb, bb+32, bb+64, bb+96

    // init L = e_0 for 4 batches (own rows: rbase, rbase+1, rbase+32, rbase+33)
    {
        const double2 z = make_double2(0.0, 0.0);
        const double2 o = make_double2(1.0, 1.0);
        const double2 v0 = (rbase == 0) ? o : z;
        *(double2*)(Lds + (rbase     ) * LSTRIDE + 4 * c    ) = v0;
        *(double2*)(Lds + (rbase     ) * LSTRIDE + 4 * c + 2) = v0;
        *(double2*)(Lds + (rbase +  1) * LSTRIDE + 4 * c    ) = z;
        *(double2*)(Lds + (rbase +  1) * LSTRIDE + 4 * c + 2) = z;
        *(double2*)(Lds + (rbase + 32) * LSTRIDE + 4 * c    ) = z;
        *(double2*)(Lds + (rbase + 32) * LSTRIDE + 4 * c + 2) = z;
        *(double2*)(Lds + (rbase + 33) * LSTRIDE + 4 * c    ) = z;
        *(double2*)(Lds + (rbase + 33) * LSTRIDE + 4 * c + 2) = z;
    }

    {   // stage site 0
        const double2* s2 = (const double2*)A8;
        double2* a2 = (double2*)As;
        #pragma unroll
        for (int q = 0; q < 8; ++q) a2[q * 512 + tid] = s2[q * 512 + tid];
    }
    __syncthreads();

    float* probOut = out + (size_t)BATCH * (NSITES * 2);

    for (int site = 0; site < NSITES; ++site) {
        // prefetch next site's A into NAMED regs (overlaps with compute below)
        const double2* nx = (const double2*)(A8 +
            (size_t)((site < NSITES - 1) ? site + 1 : site) * 8192);
        const double2 pr0 = nx[0 * 512 + tid], pr1 = nx[1 * 512 + tid];
        const double2 pr2 = nx[2 * 512 + tid], pr3 = nx[3 * 512 + tid];
        const double2 pr4 = nx[4 * 512 + tid], pr5 = nx[5 * 512 + tid];
        const double2 pr6 = nx[6 * 512 + tid], pr7 = nx[7 * 512 + tid];

        double A00=0,A01=0,A02=0,A03=0,A04=0,A05=0,A06=0,A07=0;
        double A10=0,A11=0,A12=0,A13=0,A14=0,A15=0,A16=0,A17=0;
        double A20=0,A21=0,A22=0,A23=0,A24=0,A25=0,A26=0,A27=0;
        double A30=0,A31=0,A32=0,A33=0,A34=0,A35=0,A36=0,A37=0;

        #pragma unroll 8
        for (int j = 0; j < 64; ++j) {
            const double* Lp = Lds + j * LSTRIDE + 4 * c;
            const double* Ap = As + j * 128 + rbase;
            const double2 Lv01 = *(const double2*)(Lp);
            const double2 Lv23 = *(const double2*)(Lp + 2);
            FMA4( 0, 0, 1);   // sr = rbase + {0,1}      (s=0)
            FMA4(32, 2, 3);   // sr = rbase + {32,33}    (s=0)
            FMA4(64, 4, 5);   // sr = rbase + {64,65}    (s=1)
            FMA4(96, 6, 7);   // sr = rbase + {96,97}    (s=1)
        }

        // p0 per batch: own 4 s=0 slots, then 4-level butterfly over the
        // 16-lane group (symmetric -> bit-identical on all 16 lanes).
        double P0 = A00*A00; P0=fma(A01,A01,P0); P0=fma(A02,A02,P0); P0=fma(A03,A03,P0);
        double P1 = A10*A10; P1=fma(A11,A11,P1); P1=fma(A12,A12,P1); P1=fma(A13,A13,P1);
        double P2 = A20*A20; P2=fma(A21,A21,P2); P2=fma(A22,A22,P2); P2=fma(A23,A23,P2);
        double P3 = A30*A30; P3=fma(A31,A31,P3); P3=fma(A32,A32,P3); P3=fma(A33,A33,P3);
        P0 += __shfl_xor(P0,1,64); P0 += __shfl_xor(P0,2,64); P0 += __shfl_xor(P0,4,64); P0 += __shfl_xor(P0,8,64);
        P1 += __shfl_xor(P1,1,64); P1 += __shfl_xor(P1,2,64); P1 += __shfl_xor(P1,4,64); P1 += __shfl_xor(P1,8,64);
        P2 += __shfl_xor(P2,1,64); P2 += __shfl_xor(P2,2,64); P2 += __shfl_xor(P2,4,64); P2 += __shfl_xor(P2,8,64);
        P3 += __shfl_xor(P3,1,64); P3 += __shfl_xor(P3,2,64); P3 += __shfl_xor(P3,4,64); P3 += __shfl_xor(P3,8,64);

        const float u0 = u[(size_t)(bb     ) * NSITES + site];
        const float u1 = u[(size_t)(bb + 32) * NSITES + site];
        const float u2 = u[(size_t)(bb + 64) * NSITES + site];
        const float u3 = u[(size_t)(bb + 96) * NSITES + site];
        const bool t0 = ((double)u0 >= P0);
        const bool t1 = ((double)u1 >= P1);
        const bool t2 = ((double)u2 >= P2);
        const bool t3 = ((double)u3 >= P3);
        const double s0 = t0 ? (1.0 - P0) : P0;   // p0+p1==1 by isometry
        const double s1 = t1 ? (1.0 - P1) : P1;
        const double s2 = t2 ? (1.0 - P2) : P2;
        const double s3 = t3 ? (1.0 - P3) : P3;
        const double i0 = 1.0 / sqrt(s0);
        const double i1 = 1.0 / sqrt(s1);
        const double i2 = 1.0 / sqrt(s2);
        const double i3 = 1.0 / sqrt(s3);

        // chosen T -> new L (own rows; same-wave LDS is program-ordered, no barrier)
        *(double2*)(Lds + (rbase     ) * LSTRIDE + 4*c    ) = make_double2((t0?A04:A00)*i0, (t1?A14:A10)*i1);
        *(double2*)(Lds + (rbase     ) * LSTRIDE + 4*c + 2) = make_double2((t2?A24:A20)*i2, (t3?A34:A30)*i3);
        *(double2*)(Lds + (rbase +  1) * LSTRIDE + 4*c    ) = make_double2((t0?A05:A01)*i0, (t1?A15:A11)*i1);
        *(double2*)(Lds + (rbase +  1) * LSTRIDE + 4*c + 2) = make_double2((t2?A25:A21)*i2, (t3?A35:A31)*i3);
        *(double2*)(Lds + (rbase + 32) * LSTRIDE + 4*c    ) = make_double2((t0?A06:A02)*i0, (t1?A16:A12)*i1);
        *(double2*)(Lds + (rbase + 32) * LSTRIDE + 4*c + 2) = make_double2((t2?A26:A22)*i2, (t3?A36:A32)*i3);
        *(double2*)(Lds + (rbase + 33) * LSTRIDE + 4*c    ) = make_double2((t0?A07:A03)*i0, (t1?A17:A13)*i1);
        *(double2*)(Lds + (rbase + 33) * LSTRIDE + 4*c + 2) = make_double2((t2?A27:A23)*i2, (t3?A37:A33)*i3);

        if (rlane == 0) {
            probOut[(size_t)(bb     ) * NSITES + site] = (float)s0;
            probOut[(size_t)(bb + 32) * NSITES + site] = (float)s1;
            probOut[(size_t)(bb + 64) * NSITES + site] = (float)s2;
            probOut[(size_t)(bb + 96) * NSITES + site] = (float)s3;
            *(float2*)(out + (size_t)(bb     ) * 128 + site * 2) = make_float2(t0?1.f:0.f, t0?0.f:1.f);
            *(float2*)(out + (size_t)(bb + 32) * 128 + site * 2) = make_float2(t1?1.f:0.f, t1?0.f:1.f);
            *(float2*)(out + (size_t)(bb + 64) * 128 + site * 2) = make_float2(t2?1.f:0.f, t2?0.f:1.f);
            *(float2*)(out + (size_t)(bb + 96) * 128 + site * 2) = make_float2(t3?1.f:0.f, t3?0.f:1.f);
        }

        __syncthreads();                  // all waves done reading As
        if (site < NSITES - 1) {
            double2* a2 = (double2*)As;
            a2[0*512+tid] = pr0; a2[1*512+tid] = pr1;
            a2[2*512+tid] = pr2; a2[3*512+tid] = pr3;
            a2[4*512+tid] = pr4; a2[5*512+tid] = pr5;
            a2[6*512+tid] = pr6; a2[7*512+tid] = pr7;
        }
        __syncthreads();
    }
}

extern "C" void kernel_launch(void* const* d_in, const int* in_sizes, int n_in,
                              void* d_out, int out_size, void* d_ws, size_t ws_size,
                              hipStream_t stream)
{
    const float* W = (const float*)d_in[0];   // [64,64,2,64] f32
    const float* u = (const float*)d_in[1];   // [32768,64] f32
    float* out = (float*)d_out;               // s_hat [B,64,2] then prob [B,64]
    double* A8 = (double*)d_ws;               // isometrized A, f64, 4 MiB

    hipLaunchKernelGGL(qr_site_kernel, dim3(NSITES), dim3(512), 0, stream, W, A8);
    hipLaunchKernelGGL(sample_kernel, dim3(256), dim3(512), 0, stream, A8, u, out);
}